// Round 7
// baseline (11.060 us; speedup 1.0000x reference)
//
#include <hip/hip_runtime.h>

// CenterLoss: loss = sum_b ||x[b] - centers[labels[b]]||^2 / BATCH
// x: [1024, 512] f32, labels: [1024] i32, centers: [100000, 512] f32
// out: scalar f32.
//
// Single graph node. 128 blocks x 256 threads, 8 rows/block (2 rows/wave).
// Producers publish {MAGIC tag | float bits} as ONE 64-bit relaxed atomic
// (value rides in the same word as the flag -> no fence, no second load).
// Block 0: threads 1..127 spin (relaxed u64 + s_sleep backoff) on slots,
// extract values, reset slots to 0 (poison-safe: 0xAAAA... != MAGIC and we
// never depend on initial d_ws state), reduce in FIXED order, write out[0].
// Bitwise deterministic.

#define BATCH 1024
#define FEAT 512
#define NBLK 128
#define NTHR 256
#define ROWS_PER_BLOCK (BATCH / NBLK)       // 8
#define ROWS_PER_WAVE (ROWS_PER_BLOCK / 4)  // 2
#define MAGIC 0x13572468u

__global__ __launch_bounds__(NTHR) void cl_fused_v3(
    const float* __restrict__ x,
    const int* __restrict__ labels,
    const float* __restrict__ centers,
    float* __restrict__ out,
    unsigned long long* __restrict__ slots) {
    const int b = blockIdx.x;
    const int t = threadIdx.x;
    const int wave = t >> 6;   // 0..3
    const int lane = t & 63;

    // Both rows' labels up front (independent -> overlapped latency).
    const int row0 = b * ROWS_PER_BLOCK + wave * ROWS_PER_WAVE;
    const int lab0 = labels[row0];
    const int lab1 = labels[row0 + 1];

    const float4* xr0 = reinterpret_cast<const float4*>(x + (size_t)row0 * FEAT);
    const float4* xr1 = reinterpret_cast<const float4*>(x + (size_t)(row0 + 1) * FEAT);
    const float4* cr0 = reinterpret_cast<const float4*>(centers + (size_t)lab0 * FEAT);
    const float4* cr1 = reinterpret_cast<const float4*>(centers + (size_t)lab1 * FEAT);

    // 512 floats/row = 128 float4 = 64 lanes * 2
    float4 a00 = xr0[lane];
    float4 a01 = xr0[lane + 64];
    float4 a10 = xr1[lane];
    float4 a11 = xr1[lane + 64];
    float4 c00 = cr0[lane];
    float4 c01 = cr0[lane + 64];
    float4 c10 = cr1[lane];
    float4 c11 = cr1[lane + 64];

    float s = 0.0f;
    {
        float dx = a00.x - c00.x, dy = a00.y - c00.y, dz = a00.z - c00.z, dw = a00.w - c00.w;
        s += dx * dx + dy * dy + dz * dz + dw * dw;
    }
    {
        float dx = a01.x - c01.x, dy = a01.y - c01.y, dz = a01.z - c01.z, dw = a01.w - c01.w;
        s += dx * dx + dy * dy + dz * dz + dw * dw;
    }
    {
        float dx = a10.x - c10.x, dy = a10.y - c10.y, dz = a10.z - c10.z, dw = a10.w - c10.w;
        s += dx * dx + dy * dy + dz * dz + dw * dw;
    }
    {
        float dx = a11.x - c11.x, dy = a11.y - c11.y, dz = a11.z - c11.z, dw = a11.w - c11.w;
        s += dx * dx + dy * dy + dz * dz + dw * dw;
    }

    #pragma unroll
    for (int off = 32; off > 0; off >>= 1)
        s += __shfl_down(s, off, 64);

    __shared__ float wsum[4];
    if (lane == 0) wsum[wave] = s;
    __syncthreads();
    const float blocksum = wsum[0] + wsum[1] + wsum[2] + wsum[3];

    if (b != 0) {
        if (t == 0) {
            const unsigned long long pack =
                ((unsigned long long)MAGIC << 32) | (unsigned long long)__float_as_uint(blocksum);
            __hip_atomic_store(&slots[b], pack, __ATOMIC_RELAXED, __HIP_MEMORY_SCOPE_AGENT);
        }
        return;
    }

    // --- block 0: consumer ---
    float v = 0.0f;
    if (t == 0) {
        v = blocksum;
    } else if (t < NBLK) {
        unsigned long long p;
        while (((p = __hip_atomic_load(&slots[t], __ATOMIC_RELAXED, __HIP_MEMORY_SCOPE_AGENT)) >> 32)
               != (unsigned long long)MAGIC) {
            __builtin_amdgcn_s_sleep(1);
        }
        v = __uint_as_float((unsigned int)(p & 0xFFFFFFFFull));
        // reset for next replay
        __hip_atomic_store(&slots[t], 0ull, __ATOMIC_RELAXED, __HIP_MEMORY_SCOPE_AGENT);
    }

    #pragma unroll
    for (int off = 32; off > 0; off >>= 1)
        v += __shfl_down(v, off, 64);

    __shared__ float fsum[2];
    if (lane == 0 && wave < 2) fsum[wave] = v;   // only waves 0,1 carry values (t<128)
    __syncthreads();
    if (t == 0)
        out[0] = (fsum[0] + fsum[1]) * (1.0f / (float)BATCH);
}

extern "C" void kernel_launch(void* const* d_in, const int* in_sizes, int n_in,
                              void* d_out, int out_size, void* d_ws, size_t ws_size,
                              hipStream_t stream) {
    const float* x = (const float*)d_in[0];
    const int* labels = (const int*)d_in[1];
    const float* centers = (const float*)d_in[2];
    float* out = (float*)d_out;
    unsigned long long* slots = (unsigned long long*)d_ws;  // NBLK u64

    cl_fused_v3<<<NBLK, NTHR, 0, stream>>>(x, labels, centers, out, slots);
}

// Round 8
// 9.412 us; speedup vs baseline: 1.1751x; 1.1751x over previous
//
#include <hip/hip_runtime.h>

// CenterLoss: loss = sum_b ||x[b] - centers[labels[b]]||^2 / BATCH
// x: [1024, 512] f32, labels: [1024] i32, centers: [100000, 512] f32
// out: scalar f32.
//
// Single graph node. 128 blocks x 256 threads, 8 rows/block (2 rows/wave).
// Producers publish partial[b] then flag[b]=MAGIC (release, agent scope).
// Block 0: threads 1..127 spin (relaxed + s_sleep backoff) on flags[1..127],
// one acquire fence on exit, load partials, reset flags to 0 (poison-safe:
// any initial value != MAGIC is fine; we never depend on initial d_ws state),
// reduce in fixed order, write out[0]. Bitwise deterministic.
//
// Best-measured config (R6: 9.43 us). R7's u64-packed-slot variant and
// s_sleep(1) regressed to 11.1 us; 2-kernel = 10.8; ticket+memset = 14.5;
// cooperative grid.sync = 41. Remaining time is ~7 us fixed replay overhead
// + ~2.4 us kernel (ideal memory time 0.7 us; labels->centers dependent
// gather ~0.75 us).

#define BATCH 1024
#define FEAT 512
#define NBLK 128
#define NTHR 256
#define ROWS_PER_BLOCK (BATCH / NBLK)       // 8
#define ROWS_PER_WAVE (ROWS_PER_BLOCK / 4)  // 2
#define MAGIC 0x13572468u

__global__ __launch_bounds__(NTHR) void cl_fused_v2(
    const float* __restrict__ x,
    const int* __restrict__ labels,
    const float* __restrict__ centers,
    float* __restrict__ out,
    float* __restrict__ partial,
    unsigned int* __restrict__ flags) {
    const int b = blockIdx.x;
    const int t = threadIdx.x;
    const int wave = t >> 6;   // 0..3
    const int lane = t & 63;

    // Load labels for both rows up front (independent -> overlapped latency).
    const int row0 = b * ROWS_PER_BLOCK + wave * ROWS_PER_WAVE;
    const int lab0 = labels[row0];
    const int lab1 = labels[row0 + 1];

    const float4* xr0 = reinterpret_cast<const float4*>(x + (size_t)row0 * FEAT);
    const float4* xr1 = reinterpret_cast<const float4*>(x + (size_t)(row0 + 1) * FEAT);
    const float4* cr0 = reinterpret_cast<const float4*>(centers + (size_t)lab0 * FEAT);
    const float4* cr1 = reinterpret_cast<const float4*>(centers + (size_t)lab1 * FEAT);

    // 512 floats/row = 128 float4 = 64 lanes * 2
    float4 a00 = xr0[lane];
    float4 a01 = xr0[lane + 64];
    float4 a10 = xr1[lane];
    float4 a11 = xr1[lane + 64];
    float4 c00 = cr0[lane];
    float4 c01 = cr0[lane + 64];
    float4 c10 = cr1[lane];
    float4 c11 = cr1[lane + 64];

    float s = 0.0f;
    {
        float dx = a00.x - c00.x, dy = a00.y - c00.y, dz = a00.z - c00.z, dw = a00.w - c00.w;
        s += dx * dx + dy * dy + dz * dz + dw * dw;
    }
    {
        float dx = a01.x - c01.x, dy = a01.y - c01.y, dz = a01.z - c01.z, dw = a01.w - c01.w;
        s += dx * dx + dy * dy + dz * dz + dw * dw;
    }
    {
        float dx = a10.x - c10.x, dy = a10.y - c10.y, dz = a10.z - c10.z, dw = a10.w - c10.w;
        s += dx * dx + dy * dy + dz * dz + dw * dw;
    }
    {
        float dx = a11.x - c11.x, dy = a11.y - c11.y, dz = a11.z - c11.z, dw = a11.w - c11.w;
        s += dx * dx + dy * dy + dz * dz + dw * dw;
    }

    #pragma unroll
    for (int off = 32; off > 0; off >>= 1)
        s += __shfl_down(s, off, 64);

    __shared__ float wsum[4];
    if (lane == 0) wsum[wave] = s;
    __syncthreads();
    const float blocksum = wsum[0] + wsum[1] + wsum[2] + wsum[3];

    if (b != 0) {
        if (t == 0) {
            __hip_atomic_store(&partial[b], blocksum, __ATOMIC_RELAXED, __HIP_MEMORY_SCOPE_AGENT);
            __hip_atomic_store(&flags[b], MAGIC, __ATOMIC_RELEASE, __HIP_MEMORY_SCOPE_AGENT);
        }
        return;
    }

    // --- block 0: consumer ---
    float v = 0.0f;
    if (t == 0) {
        v = blocksum;
    } else if (t < NBLK) {
        // relaxed spin with backoff; one acquire fence after.
        while (__hip_atomic_load(&flags[t], __ATOMIC_RELAXED, __HIP_MEMORY_SCOPE_AGENT) != MAGIC) {
            __builtin_amdgcn_s_sleep(2);
        }
        __builtin_amdgcn_fence(__ATOMIC_ACQUIRE, "agent");
        v = __hip_atomic_load(&partial[t], __ATOMIC_RELAXED, __HIP_MEMORY_SCOPE_AGENT);
        // reset for next replay
        __hip_atomic_store(&flags[t], 0u, __ATOMIC_RELAXED, __HIP_MEMORY_SCOPE_AGENT);
    }

    #pragma unroll
    for (int off = 32; off > 0; off >>= 1)
        v += __shfl_down(v, off, 64);

    __shared__ float fsum[2];
    if (lane == 0 && wave < 2) fsum[wave] = v;   // only waves 0,1 carry values (t<128)
    __syncthreads();
    if (t == 0)
        out[0] = (fsum[0] + fsum[1]) * (1.0f / (float)BATCH);
}

extern "C" void kernel_launch(void* const* d_in, const int* in_sizes, int n_in,
                              void* d_out, int out_size, void* d_ws, size_t ws_size,
                              hipStream_t stream) {
    const float* x = (const float*)d_in[0];
    const int* labels = (const int*)d_in[1];
    const float* centers = (const float*)d_in[2];
    float* out = (float*)d_out;
    float* partial = (float*)d_ws;                          // NBLK floats
    unsigned int* flags = (unsigned int*)(partial + NBLK);  // NBLK u32

    cl_fused_v2<<<NBLK, NTHR, 0, stream>>>(x, labels, centers, out, partial, flags);
}